// Round 5
// baseline (5128.443 us; speedup 1.0000x reference)
//
#include <hip/hip_runtime.h>

typedef unsigned short u16;
typedef unsigned int u32;
typedef unsigned long long u64;
typedef __attribute__((ext_vector_type(8))) short short8;
typedef __attribute__((ext_vector_type(4))) float f32x4;

#define T_STEPS 512
#define HF_OFF 50331648UL
#define SLOT 49152

// ws layout (bytes)
#define BCAT_OFF 18874368UL
#define HB0_OFF  18898944UL                    // 32 slots * 98304 B
#define HB1_OFF  (HB0_OFF + 32UL*98304UL)      // 4 slots
#define FLG_OFF  (HB1_OFF + 4UL*98304UL)       // u64 flags [2][514][2][64]
#define READYMASK 0x0000010101010101ULL

__device__ __forceinline__ u16 f2bf(float f) {
  union { float f; unsigned u; } v; v.f = f;
  unsigned r = (v.u + 0x7FFFu + ((v.u >> 16) & 1u)) >> 16;
  return (u16)r;
}

__device__ __forceinline__ short8 pack8(float4 f0, float4 f1) {
  short8 v;
  v[0]=(short)f2bf(f0.x); v[1]=(short)f2bf(f0.y); v[2]=(short)f2bf(f0.z); v[3]=(short)f2bf(f0.w);
  v[4]=(short)f2bf(f1.x); v[5]=(short)f2bf(f1.y); v[6]=(short)f2bf(f1.z); v[7]=(short)f2bf(f1.w);
  return v;
}

__device__ __forceinline__ float sigm(float x) { return 1.0f / (1.0f + __expf(-x)); }
__device__ __forceinline__ float tanh_f(float x) { return 1.0f - 2.0f / (__expf(2.0f * x) + 1.0f); }

__device__ __forceinline__ short8 load_sc_b128(const void* p) {
  short8 r;
  asm volatile("global_load_dwordx4 %0, %1, off sc0 sc1" : "=&v"(r) : "v"((u64)p));
  return r;  // caller must s_waitcnt vmcnt(0) before use
}
__device__ __forceinline__ u64 load_sc_b64w(const void* p) {
  u64 r;
  asm volatile("global_load_dwordx2 %0, %1, off sc0 sc1\n\ts_waitcnt vmcnt(0)"
               : "=&v"(r) : "v"((u64)p) : "memory");
  return r;
}
__device__ __forceinline__ void store_sc_b16(void* p, u32 v) {
  asm volatile("global_store_short %0, %1, off sc0 sc1" :: "v"((u64)p), "v"(v) : "memory");
}
__device__ __forceinline__ void store_sc_b8(void* p, u32 v) {
  asm volatile("global_store_byte %0, %1, off sc0 sc1" :: "v"((u64)p), "v"(v) : "memory");
}

__device__ __forceinline__ void pollu(const u64* base, int own) {
  const int ln = threadIdx.x & 63;
  for (;;) {
    u64 f = load_sc_b64w(base + ln);
    if (ln == own) f = READYMASK;
    if (__all(f == READYMASK)) break;
    __builtin_amdgcn_s_sleep(1);
  }
}

// stage 32x768 u16 tile (sc source) into LDS with pre-swizzled source offsets
__device__ __forceinline__ void stage_u16(u16* dstL, const u16* srcRow, int row, int uu) {
  short8 hv[6];
#pragma unroll
  for (int i = 0; i < 6; ++i) {
    int unit = uu + i * 16;
    int kel = (unit * 8) ^ ((row & 7) << 3);
    hv[i] = load_sc_b128(srcRow + kel);
  }
  __builtin_amdgcn_sched_barrier(0);
  asm volatile("s_waitcnt vmcnt(0)" ::: "memory");
  __builtin_amdgcn_sched_barrier(0);
#pragma unroll
  for (int i = 0; i < 6; ++i) {
    int unit = uu + i * 16;
    *(short8*)((char*)dstL + row * 1536 + unit * 16) = hv[i];
  }
}

// stage 32x768 f32 source (x input, cached loads) into LDS as bf16
__device__ __forceinline__ void stage_xf(u16* dstL, const float* srcRow, int row, int uu) {
#pragma unroll
  for (int i = 0; i < 6; ++i) {
    int unit = uu + i * 16;
    int kel = (unit * 8) ^ ((row & 7) << 3);
    float4 f0 = *(const float4*)(srcRow + kel);
    float4 f1 = *(const float4*)(srcRow + kel + 4);
    *(short8*)((char*)dstL + row * 1536 + unit * 16) = pack8(f0, f1);
  }
}

// Wr[l][j*4+g][k] bf16 (K-major; k<768 W_ih, k>=768 W_hh), gate-interleaved rows.
__global__ void prep_weights(const float* __restrict__ Wih, const float* __restrict__ Whh,
                             u16* __restrict__ Wr) {
  int idx = blockIdx.x * blockDim.x + threadIdx.x;
  if (idx >= 2 * 3072 * 192) return;
  int r = idx / 192;
  int kc = (idx - r * 192) * 8;
  int l = r / 3072;
  int rr = r - l * 3072;
  int j = rr >> 2, g = rr & 3;
  int srow = l * 3072 + g * 768 + j;
  const float* src = (kc < 768) ? (Wih + (size_t)srow * 768 + kc)
                                : (Whh + (size_t)srow * 768 + (kc - 768));
  float4 f0 = *(const float4*)src;
  float4 f1 = *(const float4*)(src + 4);
  *(short8*)(Wr + (size_t)r * 1536 + kc) = pack8(f0, f1);
}

__global__ void prep_misc(const float* __restrict__ h0, const float* __restrict__ bih,
                          const float* __restrict__ bhh, u16* __restrict__ hb0,
                          u16* __restrict__ hb1, float* __restrict__ bcat,
                          u64* __restrict__ flags) {
  int idx = blockIdx.x * blockDim.x + threadIdx.x;
  if (idx < 131584) {
    flags[idx] = (((idx >> 7) % 514) == 0) ? READYMASK : 0ULL;
  } else if (idx < 131584 + 98304) {
    int r = idx - 131584;
    int l = r / 49152, o = r - l * 49152;
    u16 v = f2bf(h0[r]);
    if (l == 0) hb0[o] = v; else hb1[o] = v;
  } else if (idx < 131584 + 98304 + 6144) {
    int q = idx - (131584 + 98304);
    int l = q / 3072, rr = q - l * 3072;
    int j = rr >> 2, g = rr & 3;
    int s = l * 3072 + g * 768 + j;
    bcat[q] = bih[s] + bhh[s];
  }
}

// 256 WGs x 512 threads: wg = layer(1b) | rg(1b) | cg(6b).
// 8 waves = 4 k-slices x 2 row-tiles; Wx/Wh VGPR-resident; x-GEMM runs one
// step ahead in the communication shadow; no global barrier.
__global__ void __launch_bounds__(512, 2)
lstm_dataflow(const float* __restrict__ x, const float* __restrict__ h0,
              const float* __restrict__ c0, const int* __restrict__ len,
              const u16* __restrict__ Wr, const float* __restrict__ bcat,
              u16* __restrict__ hb0, u16* __restrict__ hb1,
              u64* __restrict__ flags, float* __restrict__ out) {
  __shared__ u16 lAh[32 * 768];   // 48KB  h A-tile (swizzled)
  __shared__ u16 lAx[32 * 768];   // 48KB  x A-tile for NEXT step (swizzled)
  __shared__ float pP[48 * 32 * 4]; // 24KB partials [col][bloc^swz][kw^swz]

  const int tid = threadIdx.x;
  const int wv = tid >> 6;
  const int ln = tid & 63;
  const int ks = wv & 3;        // k-slice 0..3 (192 each per half)
  const int rt = wv >> 2;       // row-tile 0..1
  const int wg = blockIdx.x;
  const int layer = wg >> 7;
  const int rg = (wg >> 6) & 1;
  const int cg = wg & 63;
  const int n0 = cg * 48;
  const int row = tid >> 4;     // ingest row 0..31
  const int uu = tid & 15;
  const int arow = rt * 16 + (ln & 15);

  // ---- weights into registers: Wx (k<768), Wh (k>=768), this wave's 192-slice
  short8 Wx[3][6], Wh[3][6];
  {
    const u16* wbase = Wr + (size_t)(layer * 3072 + n0) * 1536;
#pragma unroll
    for (int ct = 0; ct < 3; ++ct)
#pragma unroll
      for (int kst = 0; kst < 6; ++kst) {
        int col = ct * 16 + (ln & 15);
        int k = ks * 192 + kst * 32 + ((ln >> 4) << 3);
        Wx[ct][kst] = *(const short8*)(wbase + (size_t)col * 1536 + k);
        Wh[ct][kst] = *(const short8*)(wbase + (size_t)col * 1536 + 768 + k);
      }
  }
  float bc[3] = {0.f, 0.f, 0.f};
  if (ks == 0) {
#pragma unroll
    for (int ct = 0; ct < 3; ++ct)
      bc[ct] = bcat[layer * 3072 + n0 + ct * 16 + (ln & 15)];
  }
  // state cells: tid<384 owns (b = rg*32 + tid/12, j = cg*12 + tid%12)
  const int cellb = tid / 12, cellj = tid - (tid / 12) * 12;
  float cReg = 0.f, hKeep = 0.f; int lenB = 0;
  if (tid < 384) {
    int b = rg * 32 + cellb, j = cg * 12 + cellj;
    cReg = c0[(size_t)(layer * 64 + b) * 768 + j];
    hKeep = h0[(size_t)(layer * 64 + b) * 768 + j];
    lenB = len[b];
  }

  f32x4 acc_x[3];
  auto run_xmfma = [&]() {
#pragma unroll
    for (int ct = 0; ct < 3; ++ct)
      acc_x[ct] = (ks == 0) ? (f32x4){bc[ct], bc[ct], bc[ct], bc[ct]}
                            : (f32x4){0.f, 0.f, 0.f, 0.f};
#pragma unroll
    for (int kst = 0; kst < 6; ++kst) {
      int kel = ks * 192 + kst * 32 + ((ln >> 4) << 3);
      short8 a = *(const short8*)((const char*)lAx + arow * 1536 + ((kel * 2) ^ ((arow & 7) << 4)));
#pragma unroll
      for (int ct = 0; ct < 3; ++ct)
        acc_x[ct] = __builtin_amdgcn_mfma_f32_16x16x32_bf16(a, Wx[ct][kst], acc_x[ct], 0, 0, 0);
    }
  };
  auto stage_x = [&](int u) {  // stage x-input of step u into lAx
    if (layer == 0) {
      stage_xf(lAx, x + ((size_t)u * 64 + rg * 32 + row) * 768, row, uu);
    } else {
      pollu(flags + ((size_t)(0 * 514 + (u + 1)) * 2 + rg) * 64, -1);
      stage_u16(lAx, hb0 + (size_t)((u + 1) & 31) * SLOT + (size_t)(rg * 32 + row) * 768, row, uu);
    }
  };

  // ---- prologue: acc_x for step 0; stage x(1)
  stage_x(0);
  __syncthreads();
  run_xmfma();
  __syncthreads();
  stage_x(1);

  for (int t = 0; t < T_STEPS; ++t) {
    // ---- 1. poll own-layer h(t), ingest into lAh ----
    pollu(flags + ((size_t)(layer * 514 + t) * 2 + rg) * 64, cg);
    {
      const u16* hp = (layer == 0) ? hb0 + (size_t)(t & 31) * SLOT
                                   : hb1 + (size_t)(t & 3) * SLOT;
      stage_u16(lAh, hp + (size_t)(rg * 32 + row) * 768, row, uu);
    }
    __syncthreads();

    // ---- 2. h-MFMA: acc = acc_x + h.Wh (this wave's k-slice) ----
    f32x4 acc[3];
#pragma unroll
    for (int ct = 0; ct < 3; ++ct) acc[ct] = acc_x[ct];
#pragma unroll
    for (int kst = 0; kst < 6; ++kst) {
      int kel = ks * 192 + kst * 32 + ((ln >> 4) << 3);
      short8 a = *(const short8*)((const char*)lAh + arow * 1536 + ((kel * 2) ^ ((arow & 7) << 4)));
#pragma unroll
      for (int ct = 0; ct < 3; ++ct)
        acc[ct] = __builtin_amdgcn_mfma_f32_16x16x32_bf16(a, Wh[ct][kst], acc[ct], 0, 0, 0);
    }

    // ---- 3. partials -> pP[col][bloc^ (col&7)][ks ^ (col&3)] ----
#pragma unroll
    for (int ct = 0; ct < 3; ++ct) {
      int col = ct * 16 + (ln & 15);
      int kwp = ks ^ (col & 3);
#pragma unroll
      for (int i = 0; i < 4; ++i) {
        int bloc = rt * 16 + ((ln >> 4) << 2) + i;
        pP[col * 128 + ((bloc ^ (col & 7)) << 2) + kwp] = acc[ct][i];
      }
    }
    __syncthreads();

    // ---- 4. reduce (4x b128) + pointwise + publish (waves 0-5) ----
    if (tid < 384) {
      float g4[4];
#pragma unroll
      for (int g = 0; g < 4; ++g) {
        int col = cellj * 4 + g;
        f32x4 v = *(const f32x4*)&pP[col * 128 + ((cellb ^ (col & 7)) << 2)];
        g4[g] = (v[0] + v[1]) + (v[2] + v[3]);
      }
      float cn = sigm(g4[1]) * cReg + sigm(g4[0]) * tanh_f(g4[2]);
      float hn = sigm(g4[3]) * tanh_f(cn);
      const bool act = t < lenB;
      float hm = act ? hn : hKeep;
      float cm = act ? cn : cReg;
      hKeep = hm; cReg = cm;
      const int bglob = rg * 32 + cellb, jglob = cg * 12 + cellj;
      u16* hout = (layer == 0) ? hb0 + (size_t)((t + 1) & 31) * SLOT
                               : hb1 + (size_t)((t + 1) & 3) * SLOT;
      store_sc_b16(hout + (size_t)bglob * 768 + jglob, (u32)f2bf(hm));
      asm volatile("s_waitcnt vmcnt(0)" ::: "memory");
      if (ln == 0) {
        char* fb = (char*)(flags + ((size_t)(layer * 514 + (t + 1)) * 2 + rg) * 64 + cg);
        store_sc_b8(fb + wv, 1u);
      }
      out[((size_t)(t * 64 + bglob) * 2 + layer) * 768 + jglob] = hm;
    }

    // ---- 5. shadow work: x-GEMM for t+1, restage x(t+2) ----
    if (t < T_STEPS - 1) run_xmfma();
    __syncthreads();
    if (t < T_STEPS - 2) stage_x(t + 2);
    if (layer == 0 && (t & 7) == 0 && t >= 8)   // throttle: L0 lead <= ~32
      pollu(flags + ((size_t)(1 * 514 + (t - 8)) * 2 + rg) * 64, -1);
  }

  // ---- final states ----
  if (tid < 384) {
    int b = rg * 32 + cellb, j = cg * 12 + cellj;
    float* hf = out + HF_OFF;
    float* cf = out + HF_OFF + 98304;
    hf[(size_t)(layer * 64 + b) * 768 + j] = hKeep;
    cf[(size_t)(layer * 64 + b) * 768 + j] = cReg;
  }
}

extern "C" void kernel_launch(void* const* d_in, const int* in_sizes, int n_in,
                              void* d_out, int out_size, void* d_ws, size_t ws_size,
                              hipStream_t stream) {
  const float* x   = (const float*)d_in[0];
  const float* h0  = (const float*)d_in[1];
  const float* c0  = (const float*)d_in[2];
  const float* Wih = (const float*)d_in[3];
  const float* Whh = (const float*)d_in[4];
  const float* bih = (const float*)d_in[5];
  const float* bhh = (const float*)d_in[6];
  const int*   len = (const int*)d_in[7];
  float* out = (float*)d_out;

  u16*   Wr    = (u16*)d_ws;
  float* bcat  = (float*)((char*)d_ws + BCAT_OFF);
  u16*   hb0   = (u16*)((char*)d_ws + HB0_OFF);
  u16*   hb1   = (u16*)((char*)d_ws + HB1_OFF);
  u64*   flags = (u64*)((char*)d_ws + FLG_OFF);

  {
    const int units = 2 * 3072 * 192;
    prep_weights<<<(units + 255) / 256, 256, 0, stream>>>(Wih, Whh, Wr);
    const int n2 = 131584 + 98304 + 6144;
    prep_misc<<<(n2 + 255) / 256, 256, 0, stream>>>(h0, bih, bhh, hb0, hb1, bcat, flags);
  }

  void* args[] = { (void*)&x, (void*)&h0, (void*)&c0, (void*)&len,
                   (void*)&Wr, (void*)&bcat, (void*)&hb0, (void*)&hb1,
                   (void*)&flags, (void*)&out };
  hipLaunchCooperativeKernel((const void*)lstm_dataflow, dim3(256), dim3(512),
                             args, 0, stream);
}

// Round 6
// 4081.680 us; speedup vs baseline: 1.2565x; 1.2565x over previous
//
#include <hip/hip_runtime.h>

typedef unsigned short u16;
typedef unsigned int u32;
typedef unsigned long long u64;
typedef __attribute__((ext_vector_type(8))) short short8;
typedef __attribute__((ext_vector_type(4))) float f32x4;

#define T_STEPS 512
#define HF_OFF 50331648UL
#define SLOT 49152

// ws layout (bytes)
#define BCAT_OFF 18874368UL
#define HB0_OFF  18898944UL                    // 32 slots * 98304 B
#define HB1_OFF  (HB0_OFF + 32UL*98304UL)      // 4 slots
#define FLG_OFF  (HB1_OFF + 4UL*98304UL)       // u32 flags [2][514][2][64]

__device__ __forceinline__ u16 f2bf(float f) {
  union { float f; unsigned u; } v; v.f = f;
  unsigned r = (v.u + 0x7FFFu + ((v.u >> 16) & 1u)) >> 16;
  return (u16)r;
}

__device__ __forceinline__ short8 pack8(float4 f0, float4 f1) {
  short8 v;
  v[0]=(short)f2bf(f0.x); v[1]=(short)f2bf(f0.y); v[2]=(short)f2bf(f0.z); v[3]=(short)f2bf(f0.w);
  v[4]=(short)f2bf(f1.x); v[5]=(short)f2bf(f1.y); v[6]=(short)f2bf(f1.z); v[7]=(short)f2bf(f1.w);
  return v;
}

__device__ __forceinline__ float sigm(float x) { return 1.0f / (1.0f + __expf(-x)); }
__device__ __forceinline__ float tanh_f(float x) { return 1.0f - 2.0f / (__expf(2.0f * x) + 1.0f); }

__device__ __forceinline__ short8 load_sc_b128(const void* p) {
  short8 r;
  asm volatile("global_load_dwordx4 %0, %1, off sc0 sc1" : "=&v"(r) : "v"((u64)p));
  return r;  // caller must s_waitcnt vmcnt(0) before use
}
__device__ __forceinline__ u32 load_sc_b32(const u32* p) {
  u32 r;
  asm volatile("global_load_dword %0, %1, off sc0 sc1\n\ts_waitcnt vmcnt(0)"
               : "=&v"(r) : "v"((u64)p) : "memory");
  return r;
}
__device__ __forceinline__ void store_sc_b32(u32* p, u32 v) {
  asm volatile("global_store_dword %0, %1, off sc0 sc1" :: "v"((u64)p), "v"(v) : "memory");
}

__device__ __forceinline__ void poll1(const u32* base, int own) {
  const int ln = threadIdx.x & 63;
  for (;;) {
    u32 f = load_sc_b32(base + ln);
    if (ln == own) f = 1u;
    if (__all(f != 0)) break;
    __builtin_amdgcn_s_sleep(1);
  }
}

// stage 32x768 u16 tile (sc source) into LDS, single latency exposure
__device__ __forceinline__ void stage_u16(u16* dstL, const u16* srcRow, int row, int uu) {
  short8 hv[6];
#pragma unroll
  for (int i = 0; i < 6; ++i) {
    int unit = uu + i * 16;
    int kel = (unit * 8) ^ ((row & 7) << 3);
    hv[i] = load_sc_b128(srcRow + kel);
  }
  __builtin_amdgcn_sched_barrier(0);
  asm volatile("s_waitcnt vmcnt(0)" ::: "memory");
  __builtin_amdgcn_sched_barrier(0);
#pragma unroll
  for (int i = 0; i < 6; ++i) {
    int unit = uu + i * 16;
    *(short8*)((char*)dstL + row * 1536 + unit * 16) = hv[i];
  }
}

// stage 32x768 f32 source (x input, cached loads) into LDS as bf16
__device__ __forceinline__ void stage_xf(u16* dstL, const float* srcRow, int row, int uu) {
#pragma unroll
  for (int i = 0; i < 6; ++i) {
    int unit = uu + i * 16;
    int kel = (unit * 8) ^ ((row & 7) << 3);
    float4 f0 = *(const float4*)(srcRow + kel);
    float4 f1 = *(const float4*)(srcRow + kel + 4);
    *(short8*)((char*)dstL + row * 1536 + unit * 16) = pack8(f0, f1);
  }
}

// Wr[l][j*4+g][k] bf16 (K-major; k<768 W_ih, k>=768 W_hh), gate-interleaved rows.
__global__ void prep_weights(const float* __restrict__ Wih, const float* __restrict__ Whh,
                             u16* __restrict__ Wr) {
  int idx = blockIdx.x * blockDim.x + threadIdx.x;
  if (idx >= 2 * 3072 * 192) return;
  int r = idx / 192;
  int kc = (idx - r * 192) * 8;
  int l = r / 3072;
  int rr = r - l * 3072;
  int j = rr >> 2, g = rr & 3;
  int srow = l * 3072 + g * 768 + j;
  const float* src = (kc < 768) ? (Wih + (size_t)srow * 768 + kc)
                                : (Whh + (size_t)srow * 768 + (kc - 768));
  float4 f0 = *(const float4*)src;
  float4 f1 = *(const float4*)(src + 4);
  *(short8*)(Wr + (size_t)r * 1536 + kc) = pack8(f0, f1);
}

__global__ void prep_misc(const float* __restrict__ h0, const float* __restrict__ bih,
                          const float* __restrict__ bhh, u16* __restrict__ hb0,
                          u16* __restrict__ hb1, float* __restrict__ bcat,
                          u32* __restrict__ flags) {
  int idx = blockIdx.x * blockDim.x + threadIdx.x;
  if (idx < 131584) {
    flags[idx] = (((idx >> 7) % 514) == 0) ? 1u : 0u;
  } else if (idx < 131584 + 98304) {
    int r = idx - 131584;
    int l = r / 49152, o = r - l * 49152;
    u16 v = f2bf(h0[r]);
    if (l == 0) hb0[o] = v; else hb1[o] = v;
  } else if (idx < 131584 + 98304 + 6144) {
    int q = idx - (131584 + 98304);
    int l = q / 3072, rr = q - l * 3072;
    int j = rr >> 2, g = rr & 3;
    int s = l * 3072 + g * 768 + j;
    bcat[q] = bih[s] + bhh[s];
  }
}

// 256 WGs x 512 threads: wg = layer(1b) | rg(1b) | cg(6b).
// 8 waves = 4 k-slices x 2 row-tiles; Wx/Wh VGPR-resident (1 WG/CU, 256-VGPR cap);
// x-GEMM one step ahead in the communication shadow; wave 7 publishes; no grid barrier.
__global__ void __launch_bounds__(512, 1)
lstm_dataflow(const float* __restrict__ x, const float* __restrict__ h0,
              const float* __restrict__ c0, const int* __restrict__ len,
              const u16* __restrict__ Wr, const float* __restrict__ bcat,
              u16* __restrict__ hb0, u16* __restrict__ hb1,
              u32* __restrict__ flags, float* __restrict__ out) {
  __shared__ u16 lAh[32 * 768];     // 48KB  h A-tile (swizzled)
  __shared__ u16 lAx[32 * 768];     // 48KB  x A-tile for NEXT step (swizzled)
  __shared__ float pP[48 * 32 * 4]; // 24KB  partials [col][bloc^swz][kw^swz]
  __shared__ u16 lH[32 * 12];       // h publish bounce

  const int tid = threadIdx.x;
  const int wv = tid >> 6;
  const int ln = tid & 63;
  const int ks = wv & 3;        // k-slice 0..3 (192 each per half)
  const int rt = wv >> 2;       // row-tile 0..1
  const int wg = blockIdx.x;
  const int layer = wg >> 7;
  const int rg = (wg >> 6) & 1;
  const int cg = wg & 63;
  const int n0 = cg * 48;
  const int row = tid >> 4;     // ingest row 0..31
  const int uu = tid & 15;
  const int arow = rt * 16 + (ln & 15);

  // ---- weights into registers: Wx (k<768), Wh (k>=768), this wave's 192-slice
  short8 Wx[3][6], Wh[3][6];
  {
    const u16* wbase = Wr + (size_t)(layer * 3072 + n0) * 1536;
#pragma unroll
    for (int ct = 0; ct < 3; ++ct)
#pragma unroll
      for (int kst = 0; kst < 6; ++kst) {
        int col = ct * 16 + (ln & 15);
        int k = ks * 192 + kst * 32 + ((ln >> 4) << 3);
        Wx[ct][kst] = *(const short8*)(wbase + (size_t)col * 1536 + k);
        Wh[ct][kst] = *(const short8*)(wbase + (size_t)col * 1536 + 768 + k);
      }
  }
  float bc[3] = {0.f, 0.f, 0.f};
  if (ks == 0) {
#pragma unroll
    for (int ct = 0; ct < 3; ++ct)
      bc[ct] = bcat[layer * 3072 + n0 + ct * 16 + (ln & 15)];
  }
  // state cells: tid<384 owns (b = rg*32 + tid/12, j = cg*12 + tid%12)
  const int cellb = tid / 12, cellj = tid - (tid / 12) * 12;
  float cReg = 0.f, hKeep = 0.f; int lenB = 0;
  if (tid < 384) {
    int b = rg * 32 + cellb, j = cg * 12 + cellj;
    cReg = c0[(size_t)(layer * 64 + b) * 768 + j];
    hKeep = h0[(size_t)(layer * 64 + b) * 768 + j];
    lenB = len[b];
  }

  f32x4 acc_x[3];
  auto run_xmfma = [&]() {
#pragma unroll
    for (int ct = 0; ct < 3; ++ct)
      acc_x[ct] = (ks == 0) ? (f32x4){bc[ct], bc[ct], bc[ct], bc[ct]}
                            : (f32x4){0.f, 0.f, 0.f, 0.f};
#pragma unroll
    for (int kst = 0; kst < 6; ++kst) {
      int kel = ks * 192 + kst * 32 + ((ln >> 4) << 3);
      short8 a = *(const short8*)((const char*)lAx + arow * 1536 + ((kel * 2) ^ ((arow & 7) << 4)));
#pragma unroll
      for (int ct = 0; ct < 3; ++ct)
        acc_x[ct] = __builtin_amdgcn_mfma_f32_16x16x32_bf16(a, Wx[ct][kst], acc_x[ct], 0, 0, 0);
    }
  };
  auto stage_x = [&](int u) {  // stage x-input of step u into lAx
    if (layer == 0) {
      stage_xf(lAx, x + ((size_t)u * 64 + rg * 32 + row) * 768, row, uu);
    } else {
      poll1(flags + ((size_t)(0 * 514 + (u + 1)) * 2 + rg) * 64, -1);
      stage_u16(lAx, hb0 + (size_t)((u + 1) & 31) * SLOT + (size_t)(rg * 32 + row) * 768, row, uu);
    }
  };

  // ---- prologue: acc_x(0) ----
  stage_x(0);
  __syncthreads();
  run_xmfma();
  __syncthreads();

  for (int t = 0; t < T_STEPS; ++t) {
    // ---- 0. issue next x-stage into lAx (completes before sync A) ----
    if (t < T_STEPS - 1) stage_x(t + 1);

    // ---- 1. poll own-layer h(t), ingest into lAh ----
    poll1(flags + ((size_t)(layer * 514 + t) * 2 + rg) * 64, cg);
    {
      const u16* hp = (layer == 0) ? hb0 + (size_t)(t & 31) * SLOT
                                   : hb1 + (size_t)(t & 3) * SLOT;
      stage_u16(lAh, hp + (size_t)(rg * 32 + row) * 768, row, uu);
    }
    __syncthreads();  // A: lAh + lAx(t+1) ready

    // ---- 2. h-MFMA: acc = acc_x + h.Wh (this wave's k-slice) ----
    f32x4 acc[3];
#pragma unroll
    for (int ct = 0; ct < 3; ++ct) acc[ct] = acc_x[ct];
#pragma unroll
    for (int kst = 0; kst < 6; ++kst) {
      int kel = ks * 192 + kst * 32 + ((ln >> 4) << 3);
      short8 a = *(const short8*)((const char*)lAh + arow * 1536 + ((kel * 2) ^ ((arow & 7) << 4)));
#pragma unroll
      for (int ct = 0; ct < 3; ++ct)
        acc[ct] = __builtin_amdgcn_mfma_f32_16x16x32_bf16(a, Wh[ct][kst], acc[ct], 0, 0, 0);
    }

    // ---- 3. partials -> pP[col][bloc^(col&7)][ks^(col&3)] ----
#pragma unroll
    for (int ct = 0; ct < 3; ++ct) {
      int col = ct * 16 + (ln & 15);
      int kwp = ks ^ (col & 3);
#pragma unroll
      for (int i = 0; i < 4; ++i) {
        int bloc = rt * 16 + ((ln >> 4) << 2) + i;
        pP[col * 128 + ((bloc ^ (col & 7)) << 2) + kwp] = acc[ct][i];
      }
    }
    __syncthreads();  // B: partials ready

    // ---- 4. reduce (4x b128) + pointwise ----
    if (tid < 384) {
      float g4[4];
#pragma unroll
      for (int g = 0; g < 4; ++g) {
        int col = cellj * 4 + g;
        f32x4 v = *(const f32x4*)&pP[col * 128 + ((cellb ^ (col & 7)) << 2)];
        g4[g] = (v[0] + v[1]) + (v[2] + v[3]);
      }
      float cn = sigm(g4[1]) * cReg + sigm(g4[0]) * tanh_f(g4[2]);
      float hn = sigm(g4[3]) * tanh_f(cn);
      const bool act = t < lenB;
      float hm = act ? hn : hKeep;
      float cm = act ? cn : cReg;
      hKeep = hm; cReg = cm;
      const int bglob = rg * 32 + cellb, jglob = cg * 12 + cellj;
      lH[cellb * 12 + cellj] = f2bf(hm);
      out[((size_t)(t * 64 + bglob) * 2 + layer) * 768 + jglob] = hm;
    }
    __syncthreads();  // C: lH ready

    // ---- 5. wave 7: coalesced publish + single flag; others: shadow x-GEMM ----
    if (wv == 7) {
      u16* hout = (layer == 0) ? hb0 + (size_t)((t + 1) & 31) * SLOT
                               : hb1 + (size_t)((t + 1) & 3) * SLOT;
      const u32* lH32 = (const u32*)lH;
#pragma unroll
      for (int it = 0; it < 3; ++it) {
        int idx = ln + it * 64;
        int r = idx / 6, w = idx - (idx / 6) * 6;
        store_sc_b32((u32*)((char*)hout + (size_t)(rg * 32 + r) * 1536 + cg * 24 + w * 4),
                     lH32[r * 6 + w]);
      }
      asm volatile("s_waitcnt vmcnt(0)" ::: "memory");
      if (ln == 0)
        store_sc_b32(flags + ((size_t)(layer * 514 + (t + 1)) * 2 + rg) * 64 + cg, 1u);
    }
    if (t < T_STEPS - 1) run_xmfma();   // acc_x(t+1), reads lAx staged at top
    if (layer == 0 && (t & 7) == 0 && t >= 8)   // throttle: L0 lead bounded
      poll1(flags + ((size_t)(1 * 514 + (t - 8)) * 2 + rg) * 64, -1);
    __syncthreads();  // D: protects lAx (next stage_x) and lH (next pointwise)
  }

  // ---- final states ----
  if (tid < 384) {
    int b = rg * 32 + cellb, j = cg * 12 + cellj;
    float* hf = out + HF_OFF;
    float* cf = out + HF_OFF + 98304;
    hf[(size_t)(layer * 64 + b) * 768 + j] = hKeep;
    cf[(size_t)(layer * 64 + b) * 768 + j] = cReg;
  }
}

extern "C" void kernel_launch(void* const* d_in, const int* in_sizes, int n_in,
                              void* d_out, int out_size, void* d_ws, size_t ws_size,
                              hipStream_t stream) {
  const float* x   = (const float*)d_in[0];
  const float* h0  = (const float*)d_in[1];
  const float* c0  = (const float*)d_in[2];
  const float* Wih = (const float*)d_in[3];
  const float* Whh = (const float*)d_in[4];
  const float* bih = (const float*)d_in[5];
  const float* bhh = (const float*)d_in[6];
  const int*   len = (const int*)d_in[7];
  float* out = (float*)d_out;

  u16*   Wr    = (u16*)d_ws;
  float* bcat  = (float*)((char*)d_ws + BCAT_OFF);
  u16*   hb0   = (u16*)((char*)d_ws + HB0_OFF);
  u16*   hb1   = (u16*)((char*)d_ws + HB1_OFF);
  u32*   flags = (u32*)((char*)d_ws + FLG_OFF);

  {
    const int units = 2 * 3072 * 192;
    prep_weights<<<(units + 255) / 256, 256, 0, stream>>>(Wih, Whh, Wr);
    const int n2 = 131584 + 98304 + 6144;
    prep_misc<<<(n2 + 255) / 256, 256, 0, stream>>>(h0, bih, bhh, hb0, hb1, bcat, flags);
  }

  void* args[] = { (void*)&x, (void*)&h0, (void*)&c0, (void*)&len,
                   (void*)&Wr, (void*)&bcat, (void*)&hb0, (void*)&hb1,
                   (void*)&flags, (void*)&out };
  hipLaunchCooperativeKernel((const void*)lstm_dataflow, dim3(256), dim3(512),
                             args, 0, stream);
}